// Round 1
// baseline (1538.211 us; speedup 1.0000x reference)
//
#include <hip/hip_runtime.h>
#include <stdint.h>
#include <type_traits>

#define NBN   25088   // 128 * 196  (TB * N)
#define NTOK  196
#define BATCH 32
#define CDIM  384
#define HDIM  1536
#define NHEAD 12

// ---------------- transpose: x (TB,C,N) -> xT (C, TB*N) ----------------
__global__ __launch_bounds__(256) void k_transpose(const float* __restrict__ x,
                                                   float* __restrict__ xT) {
  int id = blockIdx.x * 256 + threadIdx.x;   // total CDIM*NBN, exact multiple of 256
  int c = id / NBN;
  int r = id - c * NBN;          // r = b*196 + n
  int b = r / NTOK;
  int n = r - b * NTOK;
  xT[id] = x[((size_t)b * CDIM + c) * NTOK + n];
}

// ---------------- fp32 tiled GEMM: Y[M][NBN] = W[M][K] @ X[K][NBN] (+bias) -----
// input X either float or uint8 (spikes)
template <typename TIN>
__global__ __launch_bounds__(256) void k_gemm(const float* __restrict__ W,
                                              const TIN* __restrict__ X,
                                              const float* __restrict__ bias,
                                              float* __restrict__ Y,
                                              int K) {
  __shared__ float As[16][132];   // [k][m]
  __shared__ float Bs[16][132];   // [k][n]
  const int bn = blockIdx.x;      // 196 tiles of 128 cols
  const int bm = blockIdx.y;      // M/128 tiles
  const int tid = threadIdx.x;
  const int tx = tid & 15, ty = tid >> 4;

  float acc[8][8];
#pragma unroll
  for (int i = 0; i < 8; ++i)
#pragma unroll
    for (int j = 0; j < 8; ++j) acc[i][j] = 0.f;

  for (int k0 = 0; k0 < K; k0 += 16) {
    // ---- load A tile (128 x 16) ----
#pragma unroll
    for (int i = 0; i < 2; ++i) {
      int id = tid + i * 256;          // 512 float4s
      int r = id >> 2, c4 = id & 3;
      const float4 a = *reinterpret_cast<const float4*>(
          &W[(size_t)(bm * 128 + r) * K + k0 + c4 * 4]);
      As[c4 * 4 + 0][r] = a.x;
      As[c4 * 4 + 1][r] = a.y;
      As[c4 * 4 + 2][r] = a.z;
      As[c4 * 4 + 3][r] = a.w;
    }
    // ---- load B tile (16 x 128) ----
    if constexpr (std::is_same<TIN, float>::value) {
#pragma unroll
      for (int i = 0; i < 2; ++i) {
        int id = tid + i * 256;
        int r = id >> 5, c4 = id & 31;
        const float4 b = *reinterpret_cast<const float4*>(
            &X[(size_t)(k0 + r) * NBN + bn * 128 + c4 * 4]);
        *reinterpret_cast<float4*>(&Bs[r][c4 * 4]) = b;
      }
    } else {
      int r = tid >> 4, c8 = tid & 15;   // 16 rows x (16*8) bytes
      const uint2 d = *reinterpret_cast<const uint2*>(
          &X[(size_t)(k0 + r) * NBN + bn * 128 + c8 * 8]);
#pragma unroll
      for (int j = 0; j < 4; ++j) Bs[r][c8 * 8 + j]     = (float)((d.x >> (8 * j)) & 0xffu);
#pragma unroll
      for (int j = 0; j < 4; ++j) Bs[r][c8 * 8 + 4 + j] = (float)((d.y >> (8 * j)) & 0xffu);
    }
    __syncthreads();

#pragma unroll
    for (int kk = 0; kk < 16; ++kk) {
      float a[8], b[8];
      *reinterpret_cast<float4*>(&a[0]) = *reinterpret_cast<float4*>(&As[kk][ty * 8]);
      *reinterpret_cast<float4*>(&a[4]) = *reinterpret_cast<float4*>(&As[kk][ty * 8 + 4]);
      *reinterpret_cast<float4*>(&b[0]) = *reinterpret_cast<float4*>(&Bs[kk][tx * 8]);
      *reinterpret_cast<float4*>(&b[4]) = *reinterpret_cast<float4*>(&Bs[kk][tx * 8 + 4]);
#pragma unroll
      for (int i = 0; i < 8; ++i)
#pragma unroll
        for (int j = 0; j < 8; ++j) acc[i][j] = fmaf(a[i], b[j], acc[i][j]);
    }
    __syncthreads();
  }

  // ---- epilogue ----
#pragma unroll
  for (int i = 0; i < 8; ++i) {
    int row = bm * 128 + ty * 8 + i;
    float bv = bias ? bias[row] : 0.f;
    float4 o0 = {acc[i][0] + bv, acc[i][1] + bv, acc[i][2] + bv, acc[i][3] + bv};
    float4 o1 = {acc[i][4] + bv, acc[i][5] + bv, acc[i][6] + bv, acc[i][7] + bv};
    *reinterpret_cast<float4*>(&Y[(size_t)row * NBN + bn * 128 + tx * 8])     = o0;
    *reinterpret_cast<float4*>(&Y[(size_t)row * NBN + bn * 128 + tx * 8 + 4]) = o1;
  }
}

// ---------------- BN statistics: one block per channel -------------------------
__global__ __launch_bounds__(256) void k_bn_stats(const float* __restrict__ Y,
                                                  float* __restrict__ mean,
                                                  float* __restrict__ rstd) {
  const int o = blockIdx.x;
  const float* row = Y + (size_t)o * NBN;
  double s = 0.0, s2 = 0.0;
  for (int i = threadIdx.x; i < NBN; i += 256) {
    double v = (double)row[i];
    s += v;
    s2 += v * v;
  }
#pragma unroll
  for (int off = 32; off; off >>= 1) {
    s  += __shfl_down(s, off, 64);
    s2 += __shfl_down(s2, off, 64);
  }
  __shared__ double sb[2][4];
  int wid = threadIdx.x >> 6, lane = threadIdx.x & 63;
  if (lane == 0) { sb[0][wid] = s; sb[1][wid] = s2; }
  __syncthreads();
  if (threadIdx.x == 0) {
    double S  = sb[0][0] + sb[0][1] + sb[0][2] + sb[0][3];
    double S2 = sb[1][0] + sb[1][1] + sb[1][2] + sb[1][3];
    double m  = S / (double)NBN;
    double var = S2 / (double)NBN - m * m;
    mean[o] = (float)m;
    rstd[o] = (float)(1.0 / sqrt(var + 1e-5));
  }
}

// ---------------- BN apply + LIF (threshold 1.0) -------------------------------
// MODE 0: write uint8 spikes to sp
// MODE 1: write xres = addsrc + spike (float) to extra
// MODE 2: write d_out[(t*B+b), o, n] = addsrc + spike   (final layer)
template <int MODE>
__global__ __launch_bounds__(256) void k_bn_lif(const float* __restrict__ Y,
                                                const float* __restrict__ mean,
                                                const float* __restrict__ rstd,
                                                const float* __restrict__ gamma,
                                                const float* __restrict__ beta,
                                                uint8_t* __restrict__ sp,
                                                const float* __restrict__ addsrc,
                                                float* __restrict__ extra) {
  int id = blockIdx.x * 256 + threadIdx.x;   // M*6272 threads
  int o = id / (BATCH * NTOK);
  int r = id - o * (BATCH * NTOK);           // b*196 + n
  float m_ = mean[o], rs_ = rstd[o], g = gamma[o], be = beta[o];
  float mem = 0.f;
#pragma unroll
  for (int t = 0; t < 4; ++t) {
    size_t idx = (size_t)o * NBN + (size_t)t * (BATCH * NTOK) + r;
    float v = Y[idx];
    v = ((v - m_) * rs_) * g + be;
    mem = mem + (v - mem) * 0.5f;
    bool fire = (mem >= 1.0f);
    float s = fire ? 1.f : 0.f;
    mem = fire ? 0.f : mem;
    if (MODE == 0) {
      sp[idx] = (uint8_t)(fire ? 1 : 0);
    } else if (MODE == 1) {
      extra[idx] = addsrc[idx] + s;
    } else {
      int b = r / NTOK, n = r - b * NTOK;
      extra[((size_t)(t * BATCH + b) * CDIM + o) * NTOK + n] = addsrc[idx] + s;
    }
  }
}

// ---------------- attention: per (b', h) block, all 4 time steps ---------------
// kv[d,e] = sum_n k[n,d] v[n,e];  attn[n,e] = 0.125 * sum_d q[n,d] kv[d,e]
// then LIF(thr=0.5) over t with membrane per (e,n). All arithmetic exact ints.
__global__ __launch_bounds__(256) void k_attn(const uint8_t* __restrict__ spQ,
                                              const uint8_t* __restrict__ spK,
                                              const uint8_t* __restrict__ spV,
                                              uint8_t* __restrict__ spA) {
  __shared__ float mem[32 * NTOK];      // [e*196+n]
  __shared__ float kv[32][33];
  __shared__ uint8_t kb[32 * NTOK];     // [d*196+n]
  __shared__ uint8_t vb[32 * NTOK];     // [e*196+n]
  __shared__ uint8_t qb[32 * NTOK];     // [d*196+n]
  const int bh = blockIdx.x;            // 384 = 32 * 12
  const int b_ = bh / NHEAD;
  const int h  = bh - b_ * NHEAD;
  const int tid = threadIdx.x;

  for (int i = tid; i < 32 * NTOK; i += 256) mem[i] = 0.f;

  for (int t = 0; t < 4; ++t) {
    const size_t bnb = (size_t)(t * BATCH + b_) * NTOK;
    for (int i = tid; i < 32 * NTOK; i += 256) {
      int e = i / NTOK, n = i - e * NTOK;
      size_t gidx = (size_t)(h * 32 + e) * NBN + bnb + n;
      kb[i] = spK[gidx];
      vb[i] = spV[gidx];
      qb[i] = spQ[gidx];
    }
    __syncthreads();
    for (int i = tid; i < 1024; i += 256) {
      int d = i >> 5, e = i & 31;
      int ssum = 0;
      for (int n = 0; n < NTOK; ++n) ssum += (int)kb[d * NTOK + n] * (int)vb[e * NTOK + n];
      kv[d][e] = (float)ssum;
    }
    __syncthreads();
    for (int i = tid; i < 32 * NTOK; i += 256) {
      int e = i / NTOK, n = i - e * NTOK;
      float acc = 0.f;
#pragma unroll
      for (int d = 0; d < 32; ++d) acc += (float)qb[d * NTOK + n] * kv[d][e];
      float val = acc * 0.125f;
      float m = mem[i];
      m = m + (val - m) * 0.5f;
      bool fire = (m >= 0.5f);
      mem[i] = fire ? 0.f : m;
      spA[(size_t)(h * 32 + e) * NBN + bnb + n] = (uint8_t)(fire ? 1 : 0);
    }
    __syncthreads();
  }
}

// ---------------- host-side launcher ------------------------------------------
extern "C" void kernel_launch(void* const* d_in, const int* in_sizes, int n_in,
                              void* d_out, int out_size, void* d_ws, size_t ws_size,
                              hipStream_t stream) {
  const float* x          = (const float*)d_in[0];
  const float* q_w        = (const float*)d_in[1];
  const float* q_gamma    = (const float*)d_in[2];
  const float* q_beta     = (const float*)d_in[3];
  const float* k_w        = (const float*)d_in[4];
  const float* k_gamma    = (const float*)d_in[5];
  const float* k_beta     = (const float*)d_in[6];
  const float* v_w        = (const float*)d_in[7];
  const float* v_gamma    = (const float*)d_in[8];
  const float* v_beta     = (const float*)d_in[9];
  const float* proj_w     = (const float*)d_in[10];
  const float* proj_b     = (const float*)d_in[11];
  const float* proj_gamma = (const float*)d_in[12];
  const float* proj_beta  = (const float*)d_in[13];
  const float* fc1_w      = (const float*)d_in[14];
  const float* fc1_b      = (const float*)d_in[15];
  const float* bn1_gamma  = (const float*)d_in[16];
  const float* bn1_beta   = (const float*)d_in[17];
  const float* fc2_w      = (const float*)d_in[18];
  const float* fc2_b      = (const float*)d_in[19];
  const float* bn2_gamma  = (const float*)d_in[20];
  const float* bn2_beta   = (const float*)d_in[21];
  float* out = (float*)d_out;

  char* ws = (char*)d_ws;
  const size_t szY  = (size_t)CDIM * NBN * 4;   // 38,535,168
  const size_t szSp = (size_t)CDIM * NBN;       //  9,633,792

  float*   xT    = (float*)(ws + 0);
  float*   yB    = (float*)(ws + szY);
  uint8_t* spQ   = (uint8_t*)(ws + 2 * szY);
  uint8_t* spK   = spQ + szSp;
  uint8_t* spV   = spK + szSp;
  uint8_t* spA   = spV + szSp;
  float*   h1    = (float*)(ws + 0);            // 154,140,672 B: overlaps xT/yB/sp* (all dead)
  const size_t szH1 = (size_t)HDIM * NBN * 4;
  float*   xres  = (float*)(ws + szH1);
  uint8_t* h1sp  = (uint8_t*)(ws + szH1 + szY);
  float*   h2    = (float*)(ws + 0);            // overlaps h1 (dead)
  float*   mean  = (float*)(ws + szH1 + 2 * szY);
  float*   rstd  = mean + HDIM;

  const int nElemC  = CDIM * NBN;               // 9,633,792
  const dim3 gGemmC(196, 3);                    // M=384
  const dim3 gGemmH(196, 12);                   // M=1536

  // 1. transpose
  hipLaunchKernelGGL(k_transpose, dim3(nElemC / 256), dim3(256), 0, stream, x, xT);

  // 2. q / k / v branches (reuse yB)
  const float* ws_[3]  = {q_w, k_w, v_w};
  const float* gs_[3]  = {q_gamma, k_gamma, v_gamma};
  const float* bs_[3]  = {q_beta, k_beta, v_beta};
  uint8_t* sps_[3]     = {spQ, spK, spV};
  for (int br = 0; br < 3; ++br) {
    hipLaunchKernelGGL((k_gemm<float>), gGemmC, dim3(256), 0, stream,
                       ws_[br], xT, (const float*)nullptr, yB, CDIM);
    hipLaunchKernelGGL(k_bn_stats, dim3(CDIM), dim3(256), 0, stream, yB, mean, rstd);
    hipLaunchKernelGGL((k_bn_lif<0>), dim3(CDIM * BATCH * NTOK / 256), dim3(256), 0, stream,
                       yB, mean, rstd, gs_[br], bs_[br], sps_[br],
                       (const float*)nullptr, (float*)nullptr);
  }

  // 3. attention (exact integer arithmetic) -> spA
  hipLaunchKernelGGL(k_attn, dim3(BATCH * NHEAD), dim3(256), 0, stream, spQ, spK, spV, spA);

  // 4. proj GEMM (binary input) + bias
  hipLaunchKernelGGL((k_gemm<uint8_t>), gGemmC, dim3(256), 0, stream,
                     proj_w, spA, proj_b, yB, CDIM);
  hipLaunchKernelGGL(k_bn_stats, dim3(CDIM), dim3(256), 0, stream, yB, mean, rstd);
  // 5. proj BN+LIF, fused residual: xres = xT + spike
  hipLaunchKernelGGL((k_bn_lif<1>), dim3(CDIM * BATCH * NTOK / 256), dim3(256), 0, stream,
                     yB, mean, rstd, proj_gamma, proj_beta, (uint8_t*)nullptr, xT, xres);

  // 6. fc1 GEMM (continuous input) + bias
  hipLaunchKernelGGL((k_gemm<float>), gGemmH, dim3(256), 0, stream,
                     fc1_w, xres, fc1_b, h1, CDIM);
  hipLaunchKernelGGL(k_bn_stats, dim3(HDIM), dim3(256), 0, stream, h1, mean, rstd);
  hipLaunchKernelGGL((k_bn_lif<0>), dim3(HDIM * BATCH * NTOK / 256), dim3(256), 0, stream,
                     h1, mean, rstd, bn1_gamma, bn1_beta, h1sp,
                     (const float*)nullptr, (float*)nullptr);

  // 7. fc2 GEMM (binary input, K=1536) + bias
  hipLaunchKernelGGL((k_gemm<uint8_t>), gGemmC, dim3(256), 0, stream,
                     fc2_w, h1sp, fc2_b, h2, HDIM);
  hipLaunchKernelGGL(k_bn_stats, dim3(CDIM), dim3(256), 0, stream, h2, mean, rstd);
  // 8. final BN+LIF + residual, write d_out in (TB, C, N) layout
  hipLaunchKernelGGL((k_bn_lif<2>), dim3(CDIM * BATCH * NTOK / 256), dim3(256), 0, stream,
                     h2, mean, rstd, bn2_gamma, bn2_beta, (uint8_t*)nullptr, xres, out);
}